// Round 8
// baseline (369.634 us; speedup 1.0000x reference)
//
#include <hip/hip_runtime.h>

#define NG 20000
#define BOFF 12800000u   // flat-index offset of batch b+32: 32*K*N

// ---------- JAX threefry2x32, key = (0, 42) ----------
__device__ __forceinline__ void threefry2x32(unsigned x0, unsigned x1,
                                             unsigned& o0, unsigned& o1) {
  const unsigned ks0 = 0u;
  const unsigned ks1 = 42u;
  const unsigned ks2 = 0x1BD11BDAu ^ 0u ^ 42u;
  x0 += ks0; x1 += ks1;
#define TFR(r) { x0 += x1; x1 = (x1 << (r)) | (x1 >> (32 - (r))); x1 ^= x0; }
  TFR(13) TFR(15) TFR(26) TFR(6)
  x0 += ks1; x1 += ks2 + 1u;
  TFR(17) TFR(29) TFR(16) TFR(24)
  x0 += ks2; x1 += ks0 + 2u;
  TFR(13) TFR(15) TFR(26) TFR(6)
  x0 += ks0; x1 += ks1 + 3u;
  TFR(17) TFR(29) TFR(16) TFR(24)
  x0 += ks1; x1 += ks2 + 4u;
  TFR(13) TFR(15) TFR(26) TFR(6)
  x0 += ks2; x1 += ks0 + 5u;
#undef TFR
  o0 = x0; o1 = x1;
}

// JAX threefry_partitionable: bits(i) = o0 ^ o1 of threefry((0,42),(0,i))
__device__ __forceinline__ unsigned tfbits(unsigned ctr) {
  unsigned o0, o1;
  threefry2x32(0u, ctr, o0, o1);
  return o0 ^ o1;
}

// fp32 fast-screen gumbel (hw log path); abs err vs fp64 < ~1e-5
__device__ __forceinline__ float gumbel32(unsigned bits) {
  float f = __uint_as_float((bits >> 9) | 0x3f800000u) - 1.0f;
  float u = fmaxf(f, 1.17549435e-38f);
  return -__logf(-__logf(u));
}

// exact fp64 gumbel; u is a 23-bit dyadic rational, exact in double
__device__ __forceinline__ double gumbel64(unsigned bits) {
  float f = __uint_as_float((bits >> 9) | 0x3f800000u) - 1.0f;
  double u = (double)fmaxf(f, 1.17549435e-38f);
  return -log(-log(u));
}

// pack fp64 score (top 49 monotone bits) + 15-bit (32767-n): u64 max == (score, then smaller n)
__device__ __forceinline__ unsigned long long packcell(double v, int n) {
  unsigned long long u = (unsigned long long)__double_as_longlong(v);
  u = (u >> 63) ? ~u : (u | 0x8000000000000000ull);
  return (u & 0xFFFFFFFFFFFF8000ull) | (unsigned long long)(32767 - n);
}

// ---------- prep: Wf=Wk@W1k (fp64), Q, qbT; c12 table; zero cells ----------
__global__ __launch_bounds__(128) void kprep(
    const float* __restrict__ pe, const float* __restrict__ Wq,
    const float* __restrict__ bq, const float* __restrict__ Wk,
    const float* __restrict__ bk, const float* __restrict__ W1,
    const float* __restrict__ b1, const float* __restrict__ w2,
    double* __restrict__ Wfd, double* __restrict__ qbT,
    float* __restrict__ Qm, unsigned long long* __restrict__ cells,
    double2* __restrict__ c12) {
  __shared__ float L[512];
  __shared__ double Ld[128];
  const int t = threadIdx.x;
  const int bid = blockIdx.x;
  if (bid < 256) {
    L[t] = Wk[bid * 128 + t];
    __syncthreads();
    double acc = 0.0;
    #pragma unroll 8
    for (int j = 0; j < 128; ++j)
      acc = fma((double)L[j], (double)W1[(128 + j) * 128 + t], acc);
    Wfd[bid * 128 + t] = acc;
  } else if (bid < 320) {
    const int b = bid - 256;
    #pragma unroll
    for (int i = 0; i < 4; ++i) L[t + 128 * i] = pe[b * 512 + t + 128 * i];
    __syncthreads();
    double q = (double)bq[t];
    #pragma unroll 4
    for (int f = 0; f < 512; ++f)
      q = fma((double)L[f], (double)Wq[f * 128 + t], q);
    Qm[b * 128 + t] = (float)q;   // epilogue path stays fp32
    Ld[t] = q;
    __syncthreads();
    // qb[b,d=t] = Q@W1[:128] + b1 + bk@W1[128:]; store transposed qbT[d][b]
    double acc = (double)b1[t];
    #pragma unroll 4
    for (int j = 0; j < 128; ++j) {
      acc = fma(Ld[j], (double)W1[j * 128 + t], acc);
      acc = fma((double)bk[j], (double)W1[(128 + j) * 128 + t], acc);
    }
    qbT[t * 64 + b] = acc;
  } else {
    for (int i = t; i < 1280; i += 128) cells[i] = 0ull;
    const double w2d = (double)w2[t];
    c12[t] = make_double2(0.55 * w2d, 0.45 * w2d);
  }
}

// ---------- fused: kp (GEMM, LDS-staged Wfd) + sim, no kpT round-trip ----------
// block = 256 threads, 16 genes. Phase 1: thread (d = t&127, h = t>>7) computes
// kp[d][g] for genes h*8..h*8+7 (Wfd chunk-staged in LDS, ge via uniform s_load).
// Phase 2: kp -> LDS; wave wv computes sim for genes {wv, wv+4, wv+8, wv+12},
// lane = batch. FMA order identical to R7 kgemm/ksim -> simd bit-identical.
__global__ __launch_bounds__(256) void kfused(
    const float* __restrict__ ge, const double* __restrict__ Wfd,
    const double* __restrict__ qbT, const double2* __restrict__ c12,
    double* __restrict__ simd) {
  __shared__ double SB[4160];         // 32 KB Wfd chunk / (kpL 16K + simL)
  const int t = threadIdx.x;
  const int d = t & 127;
  const int h = t >> 7;
  const int wv = t >> 6;
  const int lane = t & 63;
  const int g0 = blockIdx.x * 16;     // 1250 blocks * 16 genes

  // ---- phase 1: GEMM over f in 8 chunks of 32 ----
  double acc[8];
  #pragma unroll
  for (int g = 0; g < 8; ++g) acc[g] = 0.0;
  const float* gbase = ge + (size_t)(g0 + h * 8) * 256;
  for (int c = 0; c < 8; ++c) {
    __syncthreads();
    // coop load Wfd[f = c*32 .. +32][0..128] -> SB (4096 doubles, coalesced)
    const double* src = Wfd + c * 32 * 128 + t * 16;
    double* dstL = SB + t * 16;
    #pragma unroll
    for (int i = 0; i < 16; i += 2)
      *(double2*)(dstL + i) = *(const double2*)(src + i);
    __syncthreads();
    #pragma unroll
    for (int fl = 0; fl < 32; fl += 4) {
      float4 av[8];                   // wave-uniform -> s_load_dwordx4
      #pragma unroll
      for (int g = 0; g < 8; ++g)
        av[g] = *(const float4*)(gbase + g * 256 + c * 32 + fl);
      #pragma unroll
      for (int j = 0; j < 4; ++j) {
        const double wj = SB[(fl + j) * 128 + d];
        acc[0] = fma((double)(&av[0].x)[j], wj, acc[0]);
        acc[1] = fma((double)(&av[1].x)[j], wj, acc[1]);
        acc[2] = fma((double)(&av[2].x)[j], wj, acc[2]);
        acc[3] = fma((double)(&av[3].x)[j], wj, acc[3]);
        acc[4] = fma((double)(&av[4].x)[j], wj, acc[4]);
        acc[5] = fma((double)(&av[5].x)[j], wj, acc[5]);
        acc[6] = fma((double)(&av[6].x)[j], wj, acc[6]);
        acc[7] = fma((double)(&av[7].x)[j], wj, acc[7]);
      }
    }
  }

  // ---- phase 2: kp -> LDS, then sim (4 genes/wave, lane = batch) ----
  __syncthreads();                    // all SB (Wfd) reads done
  #pragma unroll
  for (int g = 0; g < 8; ++g) SB[(h * 8 + g) * 128 + d] = acc[g];  // kpL[g][d]
  __syncthreads();

  double* simL = SB + 2048;           // [b][g], pad 17 (2-way banks)
  double s[4];
  #pragma unroll
  for (int j = 0; j < 4; ++j) s[j] = 0.0;
  for (int dd = 0; dd < 128; ++dd) {
    const double2 cc = c12[dd];                   // uniform -> s_load
    const double qv = qbT[dd * 64 + lane];        // coalesced, L1-hot
    #pragma unroll
    for (int j = 0; j < 4; ++j) {
      const double kv = SB[(wv + j * 4) * 128 + dd];  // wave-uniform broadcast
      const double tt = qv + kv;
      s[j] = fma(tt, cc.x, s[j]);
      s[j] = fma(fabs(tt), cc.y, s[j]);
    }
  }
  #pragma unroll
  for (int j = 0; j < 4; ++j) simL[lane * 17 + (wv + j * 4)] = s[j];
  __syncthreads();

  // write-out: thread -> (b = t>>2, quarter j2 = t&3), 4 doubles, 16B-aligned
  {
    const int b = t >> 2, j2 = t & 3;
    const double v0 = simL[b * 17 + j2 * 4 + 0];
    const double v1 = simL[b * 17 + j2 * 4 + 1];
    const double v2 = simL[b * 17 + j2 * 4 + 2];
    const double v3 = simL[b * 17 + j2 * 4 + 3];
    double* dst = simd + (size_t)b * NG + g0 + j2 * 4;
    *(double2*)dst = make_double2(v0, v1);
    *(double2*)(dst + 2) = make_double2(v2, v3);
  }
}

// ---------- selection (R5-proven): single-pass fp32 top-2 screen, fp64 exact at end ----------
__global__ __launch_bounds__(256) void ksel2(
    const double* __restrict__ simd, unsigned long long* __restrict__ cells) {
  const int t = threadIdx.x;
  const int wv = t >> 6;
  const int lane = t & 63;
  const int p = (int)(blockIdx.x & 7) * 4 + wv;   // pair 0..31
  const int c = (int)(blockIdx.x >> 3);           // chunk 0..246
  const int n0 = c * 81;
  const int nEnd = min(n0 + 81, NG);
  const int k = lane % 20;
  const int gi = lane / 20;
  const bool active = lane < 60;
  const double* sdA = simd + (size_t)p * NG;
  const double* sdB = simd + (size_t)(p + 32) * NG;
  const unsigned kbase = (unsigned)(p * 20 + k) * (unsigned)NG;

  float m1A = -3e38f, m2A = -3e38f, m1B = -3e38f, m2B = -3e38f;
  int n1A = -1, n2A = -1, n1B = -1, n2B = -1;
  unsigned c1A = 0, c2A = 0, c1B = 0, c2B = 0;

  for (int it = 0; it < 27; ++it) {
    const int n = n0 + it * 3 + gi;
    const bool v = active && (n < nEnd);
    const int nc = v ? n : n0;
    const unsigned idxA = kbase + (unsigned)nc;
    const unsigned bA = tfbits(idxA);
    const unsigned bB = tfbits(idxA + BOFF);
    const float s2A = v ? (float)(2.0 * sdA[nc]) : -3e38f;
    const float s2B = v ? (float)(2.0 * sdB[nc]) : -3e38f;
    const float sA = s2A + gumbel32(bA);
    const float sB = s2B + gumbel32(bB);
    if (sA > m1A) { m2A = m1A; n2A = n1A; c2A = c1A; m1A = sA; n1A = n; c1A = bA; }
    else if (sA > m2A) { m2A = sA; n2A = n; c2A = bA; }
    if (sB > m1B) { m2B = m1B; n2B = n1B; c2B = c1B; m1B = sB; n1B = n; c1B = bB; }
    else if (sB > m2B) { m2B = sB; n2B = n; c2B = bB; }
  }

  // exact fp64 for the fp32 winner (+ runner-up iff ambiguous: gap < 1e-4 >> 1e-5 screen err)
  unsigned long long pbA = 0ull, pbB = 0ull;
  if (n1A >= 0) {
    pbA = packcell(2.0 * sdA[n1A] + gumbel64(c1A), n1A);
    if (n2A >= 0 && (m1A - m2A) < 1e-4f) {
      const unsigned long long u2 = packcell(2.0 * sdA[n2A] + gumbel64(c2A), n2A);
      if (u2 > pbA) pbA = u2;
    }
  }
  if (n1B >= 0) {
    pbB = packcell(2.0 * sdB[n1B] + gumbel64(c1B), n1B);
    if (n2B >= 0 && (m1B - m2B) < 1e-4f) {
      const unsigned long long u2 = packcell(2.0 * sdB[n2B] + gumbel64(c2B), n2B);
      if (u2 > pbB) pbB = u2;
    }
  }

  // fold gi slots (lanes +20, +40), then one atomic per (batch, k)
  #pragma unroll
  for (int sh = 20; sh <= 40; sh += 20) {
    const unsigned long long oA = __shfl(pbA, lane + sh, 64);
    const unsigned long long oB = __shfl(pbB, lane + sh, 64);
    if (lane < 20) {
      if (oA > pbA) pbA = oA;
      if (oB > pbB) pbB = oB;
    }
  }
  if (lane < 20 && pbA) atomicMax(&cells[p * 20 + lane], pbA);
  if (lane < 20 && pbB) atomicMax(&cells[(p + 32) * 20 + lane], pbB);
}

// ---------- epilogue V: one wave per (b,k) GEMV; Vk + score to ws ----------
__global__ __launch_bounds__(256) void kfinalV(
    const float* __restrict__ ge, const float* __restrict__ Wv,
    const float* __restrict__ bv, const float* __restrict__ Qm,
    const unsigned long long* __restrict__ cells,
    float* __restrict__ Vws, float* __restrict__ scws) {
  const int t = threadIdx.x;
  const int wv = t >> 6;
  const int lane = t & 63;
  const int task = blockIdx.x * 4 + wv;   // 320 blocks -> 1280 tasks = (b,k)
  const int b = task / 20;
  const unsigned long long cell = cells[task];
  const int n = 32767 - (int)(cell & 0x7FFFull);
  const float* gr = ge + (size_t)n * 256;
  const float2 qv = ((const float2*)(Qm + b * 128))[lane];
  float2 V = ((const float2*)bv)[lane];
  for (int f = 0; f < 256; f += 4) {
    const float4 gv = *(const float4*)(gr + f);   // wave-uniform -> s_load
    const float2 w0 = ((const float2*)(Wv + (size_t)(f + 0) * 128))[lane];
    const float2 w1 = ((const float2*)(Wv + (size_t)(f + 1) * 128))[lane];
    const float2 w2_ = ((const float2*)(Wv + (size_t)(f + 2) * 128))[lane];
    const float2 w3 = ((const float2*)(Wv + (size_t)(f + 3) * 128))[lane];
    V.x = fmaf(gv.x, w0.x, V.x); V.y = fmaf(gv.x, w0.y, V.y);
    V.x = fmaf(gv.y, w1.x, V.x); V.y = fmaf(gv.y, w1.y, V.y);
    V.x = fmaf(gv.z, w2_.x, V.x); V.y = fmaf(gv.z, w2_.y, V.y);
    V.x = fmaf(gv.w, w3.x, V.x); V.y = fmaf(gv.w, w3.y, V.y);
  }
  ((float2*)(Vws + (size_t)task * 128))[lane] = V;
  float pr = qv.x * V.x + qv.y * V.y;
  #pragma unroll
  for (int off = 32; off; off >>= 1) pr += __shfl_xor(pr, off, 64);
  if (lane == 0) scws[task] = pr * 0.08838834764831845f;  // 1/sqrt(128)
}

// ---------- epilogue C: softmax over K=20, weighted context sum ----------
__global__ __launch_bounds__(128) void kfinalC(
    const float* __restrict__ Vws, const float* __restrict__ scws,
    float* __restrict__ out) {
  const int b = blockIdx.x;
  const int t = threadIdx.x;   // t = d
  float sc[20];
  float m = -3.0e38f;
  #pragma unroll
  for (int i = 0; i < 20; ++i) { sc[i] = scws[b * 20 + i]; m = fmaxf(m, sc[i]); }
  float s = 0.f;
  #pragma unroll
  for (int i = 0; i < 20; ++i) { sc[i] = expf(sc[i] - m); s += sc[i]; }
  const float inv = 1.0f / s;
  float acc = 0.f;
  #pragma unroll 4
  for (int i = 0; i < 20; ++i)
    acc = fmaf(sc[i] * inv, Vws[(size_t)(b * 20 + i) * 128 + t], acc);
  out[b * 128 + t] = acc;
}

extern "C" void kernel_launch(void* const* d_in, const int* in_sizes, int n_in,
                              void* d_out, int out_size, void* d_ws, size_t ws_size,
                              hipStream_t stream) {
  (void)in_sizes; (void)n_in; (void)out_size; (void)ws_size;
  const float* pe = (const float*)d_in[0];
  const float* ge = (const float*)d_in[1];
  const float* Wq = (const float*)d_in[2];
  const float* bq = (const float*)d_in[3];
  const float* Wk = (const float*)d_in[4];
  const float* bk = (const float*)d_in[5];
  const float* Wv = (const float*)d_in[6];
  const float* bvp = (const float*)d_in[7];
  const float* W1 = (const float*)d_in[8];
  const float* b1 = (const float*)d_in[9];
  const float* w2 = (const float*)d_in[10];
  // d_in[11] = b2: uniform over n -> cancels in argmax; absent from output path.

  char* w = (char*)d_ws;
  double* Wfd = (double*)w;                              // 262144 B
  double* qbT = (double*)(w + 262144);                   // 65536 B
  float* Qm = (float*)(w + 327680);                      // 32768 B
  unsigned long long* cells =
      (unsigned long long*)(w + 360448);                 // 10240 B
  double2* c12 = (double2*)(w + 370688);                 // 2048 B
  double* simd = (double*)(w + 372736);                  // 10,240,000 B
  float* Vws = (float*)(w + 10612736);                   // 655,360 B
  float* scws = (float*)(w + 11268096);                  // 5,120 B (~11.3 MB total)
  float* out = (float*)d_out;

  kprep<<<dim3(321), dim3(128), 0, stream>>>(pe, Wq, bq, Wk, bk, W1, b1, w2,
                                             Wfd, qbT, Qm, cells, c12);
  kfused<<<dim3(1250), dim3(256), 0, stream>>>(ge, Wfd, qbT, c12, simd);
  ksel2<<<dim3(1976), dim3(256), 0, stream>>>(simd, cells);
  kfinalV<<<dim3(320), dim3(256), 0, stream>>>(ge, Wv, bvp, Qm, cells, Vws, scws);
  kfinalC<<<dim3(64), dim3(128), 0, stream>>>(Vws, scws, out);
}